// Round 2
// baseline (434.478 us; speedup 1.0000x reference)
//
#include <hip/hip_runtime.h>
#include <stdint.h>

#define BB  32
#define CIN 128
#define CO  256
#define HH  64
#define WW  64
#define HW  4096
#define OH  62
#define OW  62
#define OHW 3844

typedef __attribute__((ext_vector_type(8))) short  short8;   // 8 x bf16
typedef __attribute__((ext_vector_type(4))) float  f32x4;
typedef __attribute__((ext_vector_type(4))) ushort ushort4v; // 8B
typedef __attribute__((ext_vector_type(2))) ushort ushort2v; // 4B

__device__ __forceinline__ ushort f2bf(float f) {
  uint32_t u = __builtin_bit_cast(uint32_t, f);
  u += 0x7FFFu + ((u >> 16) & 1u);
  return (ushort)(u >> 16);
}
__device__ __forceinline__ float bf2f(ushort h) {
  uint32_t u = ((uint32_t)h) << 16;
  return __builtin_bit_cast(float, u);
}

// ---- k0: transpose + bf16-cast weights: w[ci][co] -> wt[co][ci] ----
__global__ void k_wt(const float* __restrict__ w, ushort* __restrict__ wt,
                     int kdim, int ndim) {
  int e = blockIdx.x * 256 + threadIdx.x;
  if (e >= kdim * ndim) return;
  int co = e / kdim, ci = e - co * kdim;
  wt[e] = f2bf(w[(size_t)ci * ndim + co]);
}

// ---- GEMM: out NCHW bf16 [b][co][hw] = sum_ci src * wt[co][ci] + bias
// A = W (M=co, K=ci) from wt[co][ci] (K-contiguous)
// B = X (K=ci, N=hw) staged into LDS Xq[hw][ci]
// GATHER: src = fp32 x NCHW.  else: src = bf16 NCHW (row stride hw_total).
template<bool GATHER>
__global__ __launch_bounds__(512) void k_gemm(
    const void* __restrict__ src, const ushort* __restrict__ wt,
    const float* __restrict__ bias, ushort* __restrict__ out,
    int hw_total, int ktot)
{
  __shared__ union alignas(16) {
    struct { ushort Wq[256][40]; ushort Xq[64][40]; } s;  // per-kstep tiles
    ushort Cp[256][72];                                   // epilogue [co][hw]
  } U;
  __shared__ float biasS[256];

  const int t    = threadIdx.x;
  const int b    = blockIdx.y;
  const int hw0  = blockIdx.x * 64;
  const int wid  = t >> 6;
  const int lane = t & 63;
  const int wn   = wid & 3;     // co quarter (64 co)
  const int wm   = wid >> 2;    // hw half (32 hw)
  const int l15  = lane & 15;
  const int l4   = lane >> 4;

  if (t < 256) biasS[t] = bias[t];

  f32x4 acc[4][2];
  #pragma unroll
  for (int i = 0; i < 4; ++i)
    #pragma unroll
    for (int j = 0; j < 2; ++j)
      #pragma unroll
      for (int k = 0; k < 4; ++k) acc[i][j][k] = 0.f;

  const int ksteps = ktot >> 5;
  for (int ks = 0; ks < ksteps; ++ks) {
    const int ci0 = ks * 32;
    __syncthreads();   // previous mfma reads done (and biasS on first iter)

    // stage W slice: 256 co x 32 ci
    #pragma unroll
    for (int it = 0; it < 2; ++it) {
      int c  = it * 512 + t;
      int co = c >> 2, seg = c & 3;
      const ushort* p = wt + (size_t)co * ktot + ci0 + seg * 8;
      short8 v = *(const short8*)p;
      *(short8*)&U.s.Wq[co][seg * 8] = v;
    }
    // stage X slice: 64 hw x 32 ci (transpose folded into gather)
    if (t < 256) {
      int hw = t & 63, g = t >> 6;     // g: 0..3, 8 ci each
      short8 v;
      if (GATHER) {
        const float* xp = (const float*)src
            + (size_t)b * CIN * HW + (size_t)(ci0 + g * 8) * HW + hw0 + hw;
        #pragma unroll
        for (int i = 0; i < 8; ++i) v[i] = (short)f2bf(xp[(size_t)i * HW]);
      } else {
        if (hw0 + hw < hw_total) {
          const ushort* xp = (const ushort*)src
              + ((size_t)b * CO + (ci0 + g * 8)) * hw_total + hw0 + hw;
          #pragma unroll
          for (int i = 0; i < 8; ++i) v[i] = (short)xp[(size_t)i * hw_total];
        } else {
          #pragma unroll
          for (int i = 0; i < 8; ++i) v[i] = 0;
        }
      }
      *(short8*)&U.s.Xq[hw][g * 8] = v;
    }
    __syncthreads();

    short8 af[4], bx[2];
    #pragma unroll
    for (int i = 0; i < 4; ++i)
      af[i] = *(const short8*)&U.s.Wq[wn * 64 + i * 16 + l15][l4 * 8];
    #pragma unroll
    for (int j = 0; j < 2; ++j)
      bx[j] = *(const short8*)&U.s.Xq[wm * 32 + j * 16 + l15][l4 * 8];
    #pragma unroll
    for (int i = 0; i < 4; ++i)
      #pragma unroll
      for (int j = 0; j < 2; ++j)
        acc[i][j] = __builtin_amdgcn_mfma_f32_16x16x32_bf16(af[i], bx[j], acc[i][j], 0, 0, 0);
  }

  __syncthreads();   // all frag reads done before Cp overwrites Wq/Xq

  // epilogue: bias + bf16, repack to [co][hw_local]
  #pragma unroll
  for (int i = 0; i < 4; ++i) {
    #pragma unroll
    for (int j = 0; j < 2; ++j) {
      int hwl = wm * 32 + j * 16 + l15;             // D col = hw
      #pragma unroll
      for (int k = 0; k < 4; ++k) {
        int co = wn * 64 + i * 16 + l4 * 4 + k;     // D row = co
        U.Cp[co][hwl] = f2bf(acc[i][j][k] + biasS[co]);
      }
    }
  }
  __syncthreads();

  // coalesced NCHW store: 256 rows (co) x 64 bf16 (128B each)
  const size_t ob = (size_t)b * CO * (size_t)hw_total + hw0;
  if (hw0 + 64 <= hw_total) {
    #pragma unroll
    for (int p = 0; p < 4; ++p) {
      int co = p * 64 + (t >> 3), ch = t & 7;
      ushort4v lo = *(const ushort4v*)&U.Cp[co][ch * 8];
      ushort4v hi = *(const ushort4v*)&U.Cp[co][ch * 8 + 4];
      ushort* q = out + ob + (size_t)co * hw_total + ch * 8;
      *(ushort4v*)q = lo;
      *(ushort4v*)(q + 4) = hi;
    }
  } else {
    int rem = hw_total - hw0;
    #pragma unroll
    for (int p = 0; p < 2; ++p) {
      int co = p * 128 + (t >> 2);
      for (int w = (t & 3); w < rem; w += 4)
        out[ob + (size_t)co * hw_total + w] = U.Cp[co][w];
    }
  }
}

// ---- dw1: V1 (along H) + H1 (along W), VALID. One block per (b,c) plane.
__global__ __launch_bounds__(256) void k_dw1(
    const ushort* __restrict__ y1, const float* __restrict__ vw,
    const float* __restrict__ vb, const float* __restrict__ hwt,
    const float* __restrict__ hb, ushort* __restrict__ t1)
{
  __shared__ ushort P[64][66];
  const int t = threadIdx.x, c = blockIdx.x, b = blockIdx.y;
  const ushort* src = y1 + ((size_t)b * CO + c) * HW;
  #pragma unroll
  for (int k = 0; k < 8; ++k) {
    int e2 = t + k * 256;               // 0..2047 (ushort2 chunks)
    int h = e2 >> 5, w = (e2 & 31) * 2;
    *(ushort2v*)&P[h][w] = *(const ushort2v*)(src + h * WW + w);
  }
  const float v0 = vw[c * 3 + 0], v1 = vw[c * 3 + 1], v2 = vw[c * 3 + 2];
  const float h0 = hwt[c * 3 + 0], h1 = hwt[c * 3 + 1], h2 = hwt[c * 3 + 2];
  const float cst = vb[c] * (h0 + h1 + h2) + hb[c];
  __syncthreads();
  if (t < 248) {
    const int h = t >> 2, seg = t & 3;
    const int w0 = seg * 16, n = (seg == 3) ? 14 : 16;
    auto vcol = [&](int s) -> float {
      return v0 * bf2f(P[h][s]) + v1 * bf2f(P[h + 1][s]) + v2 * bf2f(P[h + 2][s]);
    };
    float c0 = vcol(w0), c1 = vcol(w0 + 1);
    ushort* ob = t1 + ((size_t)b * CO + c) * OHW + h * OW + w0;
    for (int j = 0; j < n; ++j) {
      float c2 = vcol(w0 + j + 2);
      ob[j] = f2bf(h0 * c0 + h1 * c1 + h2 * c2 + cst);
      c0 = c1; c1 = c2;
    }
  }
}

// ---- dw2: zero-pad + V2 + H2; block per (b,c); writes fp32 NCHW output.
__global__ __launch_bounds__(256) void k_dw2(
    const ushort* __restrict__ t2, const float* __restrict__ vw,
    const float* __restrict__ vb, const float* __restrict__ hwt,
    const float* __restrict__ hb, float* __restrict__ outp)
{
  __shared__ ushort P[62][66];
  const int t = threadIdx.x, c = blockIdx.x, b = blockIdx.y;
  const ushort* src = t2 + ((size_t)b * CO + c) * OHW;
  #pragma unroll
  for (int k = 0; k < 8; ++k) {
    int e2 = t + k * 256;               // ushort2 chunks, 1922 total
    if (e2 < 1922) {
      int e = e2 * 2;
      int h = e / 62, w = e - h * 62;   // pairs never straddle rows (62 even)
      *(ushort2v*)&P[h][w] = *(const ushort2v*)(src + e);
    }
  }
  const float v0 = vw[c * 3 + 0], v1 = vw[c * 3 + 1], v2 = vw[c * 3 + 2];
  const float h0 = hwt[c * 3 + 0], h1 = hwt[c * 3 + 1], h2 = hwt[c * 3 + 2];
  const float cst = vb[c] * (h0 + h1 + h2) + hb[c];
  __syncthreads();
  if (t < 248) {
    const int h = t >> 2, seg = t & 3;
    const int w0 = seg * 16, n = (seg == 3) ? 14 : 16;
    const bool rm = (h > 0), rp = (h < OH - 1);
    auto vcol = [&](int s) -> float {   // s in [-1..62]; pad outside [0,61]
      if ((unsigned)s >= (unsigned)OW) return 0.f;
      float a = v1 * bf2f(P[h][s]);
      if (rm) a += v0 * bf2f(P[h - 1][s]);
      if (rp) a += v2 * bf2f(P[h + 1][s]);
      return a;
    };
    float c0 = vcol(w0 - 1), c1 = vcol(w0);
    float* ob = outp + ((size_t)b * CO + c) * OHW + h * OW + w0;
    for (int j = 0; j < n; ++j) {
      float c2 = vcol(w0 + j + 1);
      ob[j] = h0 * c0 + h1 * c1 + h2 * c2 + cst;
      c0 = c1; c1 = c2;
    }
  }
}

extern "C" void kernel_launch(void* const* d_in, const int* in_sizes, int n_in,
                              void* d_out, int out_size, void* d_ws, size_t ws_size,
                              hipStream_t stream) {
  const float* x   = (const float*)d_in[0];
  const float* L1w = (const float*)d_in[1];
  const float* L1b = (const float*)d_in[2];
  const float* V1w = (const float*)d_in[3];
  const float* V1b = (const float*)d_in[4];
  const float* H1w = (const float*)d_in[5];
  const float* H1b = (const float*)d_in[6];
  const float* L2w = (const float*)d_in[7];
  const float* L2b = (const float*)d_in[8];
  const float* V2w = (const float*)d_in[9];
  const float* V2b = (const float*)d_in[10];
  const float* H2w = (const float*)d_in[11];
  const float* H2b = (const float*)d_in[12];

  char* ws = (char*)d_ws;
  ushort* y1n = (ushort*)ws;                                 // 67,108,864 B
  ushort* w1t = (ushort*)(ws + (size_t)67108864);            //     65,536 B
  ushort* w2t = (ushort*)(ws + (size_t)67108864 + 65536);    //    131,072 B
  ushort* t2n = (ushort*)ws;                                 // reuse y1n (dead)
  ushort* t1n = (ushort*)d_out;                              // d_out as scratch

  k_wt<<<dim3((CIN * CO + 255) / 256), dim3(256), 0, stream>>>(L1w, w1t, CIN, CO);
  k_wt<<<dim3((CO * CO + 255) / 256), dim3(256), 0, stream>>>(L2w, w2t, CO, CO);

  // L1: x (fp32 NCHW) -> y1n bf16 NCHW [b][256][4096]
  k_gemm<true><<<dim3(HW / 64, BB), dim3(512), 0, stream>>>(
      (const void*)x, w1t, L1b, y1n, HW, CIN);

  // V1+H1 -> t1n bf16 NCHW [b][256][3844] (in d_out)
  k_dw1<<<dim3(CO, BB), dim3(256), 0, stream>>>(y1n, V1w, V1b, H1w, H1b, t1n);

  // L2: t1n -> t2n bf16 NCHW [b][256][3844]
  k_gemm<false><<<dim3((OHW + 63) / 64, BB), dim3(512), 0, stream>>>(
      (const void*)t1n, w2t, L2b, t2n, OHW, CO);

  // pad + V2 + H2 -> d_out fp32 NCHW
  k_dw2<<<dim3(CO, BB), dim3(256), 0, stream>>>(t2n, V2w, V2b, H2w, H2b, (float*)d_out);
}

// Round 3
// 329.827 us; speedup vs baseline: 1.3173x; 1.3173x over previous
//
#include <hip/hip_runtime.h>
#include <stdint.h>

#define BB  32
#define CIN 128
#define CO  256
#define HH  64
#define WW  64
#define HW  4096
#define OH  62
#define OW  62
#define OHW 3844

typedef __attribute__((ext_vector_type(8))) short  short8;   // 8 x bf16
typedef __attribute__((ext_vector_type(4))) float  f32x4;
typedef __attribute__((ext_vector_type(4))) ushort ushort4v; // 8B
typedef __attribute__((ext_vector_type(2))) ushort ushort2v; // 4B
typedef __attribute__((ext_vector_type(2))) float  f32x2;    // 8B

__device__ __forceinline__ ushort f2bf(float f) {
  uint32_t u = __builtin_bit_cast(uint32_t, f);
  u += 0x7FFFu + ((u >> 16) & 1u);
  return (ushort)(u >> 16);
}
__device__ __forceinline__ float bf2f(ushort h) {
  uint32_t u = ((uint32_t)h) << 16;
  return __builtin_bit_cast(float, u);
}

// ---- k0: transpose + bf16-cast weights: w[ci][co] -> wt[co][ci] ----
__global__ void k_wt(const float* __restrict__ w, ushort* __restrict__ wt,
                     int kdim, int ndim) {
  int e = blockIdx.x * 256 + threadIdx.x;
  if (e >= kdim * ndim) return;
  int co = e / kdim, ci = e - co * kdim;
  wt[e] = f2bf(w[(size_t)ci * ndim + co]);
}

// ---- GEMM: out NCHW bf16 [b][co][hw] = sum_ci src * wt[co][ci] + bias
template<bool GATHER>
__global__ __launch_bounds__(512) void k_gemm(
    const void* __restrict__ src, const ushort* __restrict__ wt,
    const float* __restrict__ bias, ushort* __restrict__ out,
    int hw_total, int ktot)
{
  __shared__ union alignas(16) {
    struct { ushort Wq[256][40]; ushort Xq[64][40]; } s;  // per-kstep tiles
    ushort Cp[256][72];                                   // epilogue [co][hw]
  } U;
  __shared__ float biasS[256];

  const int t    = threadIdx.x;
  const int b    = blockIdx.y;
  const int hw0  = blockIdx.x * 64;
  const int wid  = t >> 6;
  const int lane = t & 63;
  const int wn   = wid & 3;     // co quarter (64 co)
  const int wm   = wid >> 2;    // hw half (32 hw)
  const int l15  = lane & 15;
  const int l4   = lane >> 4;

  if (t < 256) biasS[t] = bias[t];

  f32x4 acc[4][2];
  #pragma unroll
  for (int i = 0; i < 4; ++i)
    #pragma unroll
    for (int j = 0; j < 2; ++j)
      #pragma unroll
      for (int k = 0; k < 4; ++k) acc[i][j][k] = 0.f;

  const int ksteps = ktot >> 5;
  for (int ks = 0; ks < ksteps; ++ks) {
    const int ci0 = ks * 32;
    __syncthreads();

    #pragma unroll
    for (int it = 0; it < 2; ++it) {
      int c  = it * 512 + t;
      int co = c >> 2, seg = c & 3;
      const ushort* p = wt + (size_t)co * ktot + ci0 + seg * 8;
      short8 v = *(const short8*)p;
      *(short8*)&U.s.Wq[co][seg * 8] = v;
    }
    if (t < 256) {
      int hw = t & 63, g = t >> 6;
      short8 v;
      if (GATHER) {
        const float* xp = (const float*)src
            + (size_t)b * CIN * HW + (size_t)(ci0 + g * 8) * HW + hw0 + hw;
        #pragma unroll
        for (int i = 0; i < 8; ++i) v[i] = (short)f2bf(xp[(size_t)i * HW]);
      } else {
        if (hw0 + hw < hw_total) {
          const ushort* xp = (const ushort*)src
              + ((size_t)b * CO + (ci0 + g * 8)) * hw_total + hw0 + hw;
          #pragma unroll
          for (int i = 0; i < 8; ++i) v[i] = (short)xp[(size_t)i * hw_total];
        } else {
          #pragma unroll
          for (int i = 0; i < 8; ++i) v[i] = 0;
        }
      }
      *(short8*)&U.s.Xq[hw][g * 8] = v;
    }
    __syncthreads();

    short8 af[4], bx[2];
    #pragma unroll
    for (int i = 0; i < 4; ++i)
      af[i] = *(const short8*)&U.s.Wq[wn * 64 + i * 16 + l15][l4 * 8];
    #pragma unroll
    for (int j = 0; j < 2; ++j)
      bx[j] = *(const short8*)&U.s.Xq[wm * 32 + j * 16 + l15][l4 * 8];
    #pragma unroll
    for (int i = 0; i < 4; ++i)
      #pragma unroll
      for (int j = 0; j < 2; ++j)
        acc[i][j] = __builtin_amdgcn_mfma_f32_16x16x32_bf16(af[i], bx[j], acc[i][j], 0, 0, 0);
  }

  __syncthreads();

  #pragma unroll
  for (int i = 0; i < 4; ++i) {
    #pragma unroll
    for (int j = 0; j < 2; ++j) {
      int hwl = wm * 32 + j * 16 + l15;
      #pragma unroll
      for (int k = 0; k < 4; ++k) {
        int co = wn * 64 + i * 16 + l4 * 4 + k;
        U.Cp[co][hwl] = f2bf(acc[i][j][k] + biasS[co]);
      }
    }
  }
  __syncthreads();

  const size_t ob = (size_t)b * CO * (size_t)hw_total + hw0;
  if (hw0 + 64 <= hw_total) {
    #pragma unroll
    for (int p = 0; p < 4; ++p) {
      int co = p * 64 + (t >> 3), ch = t & 7;
      ushort4v lo = *(const ushort4v*)&U.Cp[co][ch * 8];
      ushort4v hi = *(const ushort4v*)&U.Cp[co][ch * 8 + 4];
      ushort* q = out + ob + (size_t)co * hw_total + ch * 8;
      *(ushort4v*)q = lo;
      *(ushort4v*)(q + 4) = hi;
    }
  } else {
    int rem = hw_total - hw0;
    #pragma unroll
    for (int p = 0; p < 2; ++p) {
      int co = p * 128 + (t >> 2);
      for (int w = (t & 3); w < rem; w += 4)
        out[ob + (size_t)co * hw_total + w] = U.Cp[co][w];
    }
  }
}

// ---- dw1: V1 (along H) + H1 (along W), VALID. Block = (b,c) plane.
// 8 groups of 32 lanes; group g owns output rows [8g, 8g+7]; lane l owns
// output cols 2l, 2l+1. Row-serial pending-sum recurrence for the vertical
// tap; __shfl for neighbor columns' vertical sums; all mem ops coalesced.
__global__ __launch_bounds__(256) void k_dw1(
    const ushort* __restrict__ y1, const float* __restrict__ vw,
    const float* __restrict__ vb, const float* __restrict__ hwv,
    const float* __restrict__ hb, ushort* __restrict__ t1)
{
  const int t = threadIdx.x, c = blockIdx.x, b = blockIdx.y;
  const int g = t >> 5, l = t & 31;
  const float v0 = vw[c * 3 + 0], v1 = vw[c * 3 + 1], v2 = vw[c * 3 + 2];
  const float q0 = hwv[c * 3 + 0], q1 = hwv[c * 3 + 1], q2 = hwv[c * 3 + 2];
  const float cst = vb[c] * (q0 + q1 + q2) + hb[c];

  const ushort* src = y1 + ((size_t)b * CO + c) * HW;
  ushort*       dst = t1 + ((size_t)b * CO + c) * OHW;
  const int h0s  = g * 8;
  const int hend = (h0s + 7 < OH - 1) ? h0s + 7 : OH - 1;   // 61
  const int rend = (h0s + 9 < HH - 1) ? h0s + 9 : HH - 1;   // 63
  const int w0 = 2 * l;                                     // 0..62

  float p0a = 0.f, p0b = 0.f, p1a = 0.f, p1b = 0.f;
  for (int r = h0s; r <= rend; ++r) {
    ushort2v px = *(const ushort2v*)(src + r * WW + w0);
    float xa = bf2f(px[0]), xb = bf2f(px[1]);
    float vva = p0a + v2 * xa, vvb = p0b + v2 * xb;   // vertical sum rows r-2..r
    p0a = p1a + v1 * xa;  p0b = p1b + v1 * xb;
    p1a = v0 * xa;        p1b = v0 * xb;
    float vvc = __shfl_down(vva, 1, 32);              // vv[w0+2]
    float vvd = __shfl_down(vvb, 1, 32);              // vv[w0+3]
    int h = r - 2;
    if (h >= h0s && h <= hend && l < 31) {
      ushort2v o;
      o[0] = f2bf(cst + q0 * vva + q1 * vvb + q2 * vvc);
      o[1] = f2bf(cst + q0 * vvb + q1 * vvc + q2 * vvd);
      *(ushort2v*)(dst + h * OW + w0) = o;
    }
  }
}

// ---- dw2: zero-pad + V2 + H2; block = (b,c); writes fp32 NCHW output.
__global__ __launch_bounds__(256) void k_dw2(
    const ushort* __restrict__ t2, const float* __restrict__ vw,
    const float* __restrict__ vb, const float* __restrict__ hwv,
    const float* __restrict__ hb, float* __restrict__ outp)
{
  const int t = threadIdx.x, c = blockIdx.x, b = blockIdx.y;
  const int g = t >> 5, l = t & 31;
  const float v0 = vw[c * 3 + 0], v1 = vw[c * 3 + 1], v2 = vw[c * 3 + 2];
  const float q0 = hwv[c * 3 + 0], q1 = hwv[c * 3 + 1], q2 = hwv[c * 3 + 2];
  const float cst = vb[c] * (q0 + q1 + q2) + hb[c];

  const ushort* src = t2   + ((size_t)b * CO + c) * OHW;
  float*        dst = outp + ((size_t)b * CO + c) * OHW;
  const int h0s  = g * 8;
  const int hend = (h0s + 7 < OH - 1) ? h0s + 7 : OH - 1;   // 61
  const int w0 = 2 * l;                                     // 0..62; l=31 pad lane

  float p0a = 0.f, p0b = 0.f, p1a = 0.f, p1b = 0.f;
  for (int r = h0s - 1; r <= hend + 1; ++r) {
    float xa = 0.f, xb = 0.f;
    if (r >= 0 && r < OH && l < 31) {          // rows/cols outside: zero pad
      ushort2v px = *(const ushort2v*)(src + r * OW + w0);
      xa = bf2f(px[0]); xb = bf2f(px[1]);
    }
    float vva = p0a + v2 * xa, vvb = p0b + v2 * xb;   // vertical rows r-2..r (padded)
    p0a = p1a + v1 * xa;  p0b = p1b + v1 * xb;
    p1a = v0 * xa;        p1b = v0 * xb;
    float vvL = __shfl_up(vvb, 1, 32);                // vv[w0-1]
    float vvR = __shfl_down(vva, 1, 32);              // vv[w0+2] (lane31 gives 0)
    if (l == 0) vvL = 0.f;                            // col -1 pad
    int h = r - 1;
    if (h >= h0s && h <= hend && l < 31) {
      f32x2 o;
      o[0] = cst + q0 * vvL + q1 * vva + q2 * vvb;
      o[1] = cst + q0 * vva + q1 * vvb + q2 * vvR;
      *(f32x2*)(dst + h * OW + w0) = o;
    }
  }
}

extern "C" void kernel_launch(void* const* d_in, const int* in_sizes, int n_in,
                              void* d_out, int out_size, void* d_ws, size_t ws_size,
                              hipStream_t stream) {
  const float* x   = (const float*)d_in[0];
  const float* L1w = (const float*)d_in[1];
  const float* L1b = (const float*)d_in[2];
  const float* V1w = (const float*)d_in[3];
  const float* V1b = (const float*)d_in[4];
  const float* H1w = (const float*)d_in[5];
  const float* H1b = (const float*)d_in[6];
  const float* L2w = (const float*)d_in[7];
  const float* L2b = (const float*)d_in[8];
  const float* V2w = (const float*)d_in[9];
  const float* V2b = (const float*)d_in[10];
  const float* H2w = (const float*)d_in[11];
  const float* H2b = (const float*)d_in[12];

  char* ws = (char*)d_ws;
  ushort* y1n = (ushort*)ws;                                 // 67,108,864 B
  ushort* w1t = (ushort*)(ws + (size_t)67108864);            //     65,536 B
  ushort* w2t = (ushort*)(ws + (size_t)67108864 + 65536);    //    131,072 B
  ushort* t2n = (ushort*)ws;                                 // reuse y1n (dead)
  ushort* t1n = (ushort*)d_out;                              // d_out as scratch

  k_wt<<<dim3((CIN * CO + 255) / 256), dim3(256), 0, stream>>>(L1w, w1t, CIN, CO);
  k_wt<<<dim3((CO * CO + 255) / 256), dim3(256), 0, stream>>>(L2w, w2t, CO, CO);

  // L1: x (fp32 NCHW) -> y1n bf16 NCHW [b][256][4096]
  k_gemm<true><<<dim3(HW / 64, BB), dim3(512), 0, stream>>>(
      (const void*)x, w1t, L1b, y1n, HW, CIN);

  // V1+H1 -> t1n bf16 NCHW [b][256][3844] (in d_out)
  k_dw1<<<dim3(CO, BB), dim3(256), 0, stream>>>(y1n, V1w, V1b, H1w, H1b, t1n);

  // L2: t1n -> t2n bf16 NCHW [b][256][3844]
  k_gemm<false><<<dim3((OHW + 63) / 64, BB), dim3(512), 0, stream>>>(
      (const void*)t1n, w2t, L2b, t2n, OHW, CO);

  // pad + V2 + H2 -> d_out fp32 NCHW
  k_dw2<<<dim3(CO, BB), dim3(256), 0, stream>>>(t2n, V2w, V2b, H2w, H2b, (float*)d_out);
}

// Round 4
// 320.206 us; speedup vs baseline: 1.3569x; 1.0300x over previous
//
#include <hip/hip_runtime.h>
#include <stdint.h>

#define BB  32
#define CIN 128
#define CO  256
#define HH  64
#define WW  64
#define HW  4096
#define OH  62
#define OW  62
#define OHW 3844
#define OPST 3968   // padded plane stride for t1/t2 (= 31*128)

typedef __attribute__((ext_vector_type(8))) short  short8;   // 8 x bf16
typedef __attribute__((ext_vector_type(4))) float  f32x4;
typedef __attribute__((ext_vector_type(2))) ushort ushort2v; // 4B
typedef __attribute__((ext_vector_type(2))) float  f32x2;    // 8B
typedef __attribute__((ext_vector_type(2))) uint32_t uint2v; // 8B

__device__ __forceinline__ ushort f2bf(float f) {
  uint32_t u = __builtin_bit_cast(uint32_t, f);
  u += 0x7FFFu + ((u >> 16) & 1u);
  return (ushort)(u >> 16);
}
__device__ __forceinline__ float bf2f(ushort h) {
  uint32_t u = ((uint32_t)h) << 16;
  return __builtin_bit_cast(float, u);
}
// swizzled byte offset of logical 16B chunk C (XOR chunk bits 0-2 with bits 2-4)
__device__ __forceinline__ int swz16(int C) { return (C ^ ((C >> 2) & 7)) << 4; }

// ---- k0: transpose + bf16-cast weights: w[ci][co] -> wt[co][ci] ----
__global__ void k_wt(const float* __restrict__ w, ushort* __restrict__ wt,
                     int kdim, int ndim) {
  int e = blockIdx.x * 256 + threadIdx.x;
  if (e >= kdim * ndim) return;
  int co = e / kdim, ci = e - co * kdim;
  wt[e] = f2bf(w[(size_t)ci * ndim + co]);
}

// ---- GEMM: out NCHW bf16 [b][co][pst_out] = sum_ci src * wt[co][ci] + bias
// Tile: 256 co x 128 hw, 8 waves; wave w owns co [32w, 32w+32).
// A = X (rows = hw, K-contig from swizzled Xq), B = W (cols = co, from Wq).
// D: col(lane&15)=co, row((lane>>4)*4+k)=hw -> lane holds 4 consecutive hw.
template<bool GATHER>
__global__ __launch_bounds__(512, 4) void k_gemm(
    const void* __restrict__ src, const ushort* __restrict__ wt,
    const float* __restrict__ bias, ushort* __restrict__ out,
    int pst_src, int pst_out, int ktot)
{
  __shared__ ushort Wq[256 * 32];   // 16 KB, swizzled 16B chunks
  __shared__ ushort Xq[128 * 32];   //  8 KB, swizzled 16B chunks

  const int t = threadIdx.x;
  const int b = blockIdx.y;
  const int hw0 = blockIdx.x * 128;
  const int w = t >> 6, lane = t & 63, l15 = lane & 15, l4 = lane >> 4;

  // loop-invariant swizzled byte offsets
  int afoff0, afoff1, bxoff[8], wstoff0, wstoff1, xstoff;
  afoff0 = swz16((w * 32 + l15) * 4 + l4);
  afoff1 = swz16((w * 32 + 16 + l15) * 4 + l4);
  #pragma unroll
  for (int j = 0; j < 8; ++j) bxoff[j] = swz16((j * 16 + l15) * 4 + l4);
  wstoff0 = swz16(t);
  wstoff1 = swz16(512 + t);
  const int xhw = t & 127, xg = t >> 7;
  xstoff = swz16(xhw * 4 + xg);

  const float bias0 = bias[w * 32 + l15];
  const float bias1 = bias[w * 32 + 16 + l15];

  f32x4 acc[2][8];
  #pragma unroll
  for (int i = 0; i < 2; ++i)
    #pragma unroll
    for (int j = 0; j < 8; ++j)
      #pragma unroll
      for (int k = 0; k < 4; ++k) acc[i][j][k] = 0.f;

  const int ksteps = ktot >> 5;
  for (int ks = 0; ks < ksteps; ++ks) {
    const int ci0 = ks * 32;
    __syncthreads();
    // ---- stage W: 256co x 32ci (2 chunks/thread) ----
    {
      int c0 = t, co0 = c0 >> 2, s0 = c0 & 3;
      short8 v0 = *(const short8*)(wt + (size_t)co0 * ktot + ci0 + s0 * 8);
      *(short8*)((char*)Wq + wstoff0) = v0;
      int c1 = 512 + t, co1 = c1 >> 2, s1 = c1 & 3;
      short8 v1 = *(const short8*)(wt + (size_t)co1 * ktot + ci0 + s1 * 8);
      *(short8*)((char*)Wq + wstoff1) = v1;
    }
    // ---- stage X: 128hw x 32ci (1 chunk/thread, transpose gather) ----
    {
      short8 xv;
      if (GATHER) {
        const float* xp = (const float*)src
            + ((size_t)b * ktot + ci0 + xg * 8) * pst_src + hw0 + xhw;
        #pragma unroll
        for (int ii = 0; ii < 8; ++ii) xv[ii] = (short)f2bf(xp[(size_t)ii * pst_src]);
      } else {
        const ushort* xp = (const ushort*)src
            + ((size_t)b * ktot + ci0 + xg * 8) * pst_src + hw0 + xhw;
        #pragma unroll
        for (int ii = 0; ii < 8; ++ii) xv[ii] = (short)xp[(size_t)ii * pst_src];
      }
      *(short8*)((char*)Xq + xstoff) = xv;
    }
    __syncthreads();

    // ---- compute: 16 MFMA / wave / kstep ----
    short8 af0 = *(const short8*)((char*)Wq + afoff0);
    short8 af1 = *(const short8*)((char*)Wq + afoff1);
    #pragma unroll
    for (int j = 0; j < 8; ++j) {
      short8 bx = *(const short8*)((char*)Xq + bxoff[j]);
      acc[0][j] = __builtin_amdgcn_mfma_f32_16x16x32_bf16(bx, af0, acc[0][j], 0, 0, 0);
      acc[1][j] = __builtin_amdgcn_mfma_f32_16x16x32_bf16(bx, af1, acc[1][j], 0, 0, 0);
    }
  }

  // ---- epilogue: direct vectorized stores (4 consecutive hw per lane) ----
  #pragma unroll
  for (int i = 0; i < 2; ++i) {
    const float bi = i ? bias1 : bias0;
    const int co = w * 32 + i * 16 + l15;
    ushort* ob = out + (size_t)(b * CO + co) * pst_out + hw0 + l4 * 4;
    #pragma unroll
    for (int j = 0; j < 8; ++j) {
      uint32_t lo = (uint32_t)f2bf(acc[i][j][0] + bi)
                  | ((uint32_t)f2bf(acc[i][j][1] + bi) << 16);
      uint32_t hi = (uint32_t)f2bf(acc[i][j][2] + bi)
                  | ((uint32_t)f2bf(acc[i][j][3] + bi) << 16);
      uint2v v; v[0] = lo; v[1] = hi;
      *(uint2v*)(ob + j * 16) = v;
    }
  }
}

// ---- dw1: V1 (along H) + H1 (along W), VALID. Block = (b,c) plane.
// 8 groups of 32 lanes; group g owns output rows [8g, 8g+7]; lane l owns
// output cols 2l, 2l+1. Output plane stride padded to OPST.
__global__ __launch_bounds__(256) void k_dw1(
    const ushort* __restrict__ y1, const float* __restrict__ vw,
    const float* __restrict__ vb, const float* __restrict__ hwv,
    const float* __restrict__ hb, ushort* __restrict__ t1)
{
  const int t = threadIdx.x, c = blockIdx.x, b = blockIdx.y;
  const int g = t >> 5, l = t & 31;
  const float v0 = vw[c * 3 + 0], v1 = vw[c * 3 + 1], v2 = vw[c * 3 + 2];
  const float q0 = hwv[c * 3 + 0], q1 = hwv[c * 3 + 1], q2 = hwv[c * 3 + 2];
  const float cst = vb[c] * (q0 + q1 + q2) + hb[c];

  const ushort* src = y1 + ((size_t)b * CO + c) * HW;
  ushort*       dst = t1 + ((size_t)b * CO + c) * OPST;
  const int h0s  = g * 8;
  const int hend = (h0s + 7 < OH - 1) ? h0s + 7 : OH - 1;   // 61
  const int rend = (h0s + 9 < HH - 1) ? h0s + 9 : HH - 1;   // 63
  const int w0 = 2 * l;                                     // 0..62

  float p0a = 0.f, p0b = 0.f, p1a = 0.f, p1b = 0.f;
  for (int r = h0s; r <= rend; ++r) {
    ushort2v px = *(const ushort2v*)(src + r * WW + w0);
    float xa = bf2f(px[0]), xb = bf2f(px[1]);
    float vva = p0a + v2 * xa, vvb = p0b + v2 * xb;   // vertical sum rows r-2..r
    p0a = p1a + v1 * xa;  p0b = p1b + v1 * xb;
    p1a = v0 * xa;        p1b = v0 * xb;
    float vvc = __shfl_down(vva, 1, 32);              // vv[w0+2]
    float vvd = __shfl_down(vvb, 1, 32);              // vv[w0+3]
    int h = r - 2;
    if (h >= h0s && h <= hend && l < 31) {
      ushort2v o;
      o[0] = f2bf(cst + q0 * vva + q1 * vvb + q2 * vvc);
      o[1] = f2bf(cst + q0 * vvb + q1 * vvc + q2 * vvd);
      *(ushort2v*)(dst + h * OW + w0) = o;
    }
  }
}

// ---- dw2: zero-pad + V2 + H2; block = (b,c); reads padded-stride t2,
// writes exact fp32 NCHW output.
__global__ __launch_bounds__(256) void k_dw2(
    const ushort* __restrict__ t2, const float* __restrict__ vw,
    const float* __restrict__ vb, const float* __restrict__ hwv,
    const float* __restrict__ hb, float* __restrict__ outp)
{
  const int t = threadIdx.x, c = blockIdx.x, b = blockIdx.y;
  const int g = t >> 5, l = t & 31;
  const float v0 = vw[c * 3 + 0], v1 = vw[c * 3 + 1], v2 = vw[c * 3 + 2];
  const float q0 = hwv[c * 3 + 0], q1 = hwv[c * 3 + 1], q2 = hwv[c * 3 + 2];
  const float cst = vb[c] * (q0 + q1 + q2) + hb[c];

  const ushort* src = t2   + ((size_t)b * CO + c) * OPST;
  float*        dst = outp + ((size_t)b * CO + c) * OHW;
  const int h0s  = g * 8;
  const int hend = (h0s + 7 < OH - 1) ? h0s + 7 : OH - 1;   // 61
  const int w0 = 2 * l;                                     // 0..62; l=31 pad lane

  float p0a = 0.f, p0b = 0.f, p1a = 0.f, p1b = 0.f;
  for (int r = h0s - 1; r <= hend + 1; ++r) {
    float xa = 0.f, xb = 0.f;
    if (r >= 0 && r < OH && l < 31) {          // rows/cols outside: zero pad
      ushort2v px = *(const ushort2v*)(src + r * OW + w0);
      xa = bf2f(px[0]); xb = bf2f(px[1]);
    }
    float vva = p0a + v2 * xa, vvb = p0b + v2 * xb;   // vertical rows r-2..r (padded)
    p0a = p1a + v1 * xa;  p0b = p1b + v1 * xb;
    p1a = v0 * xa;        p1b = v0 * xb;
    float vvL = __shfl_up(vvb, 1, 32);                // vv[w0-1]
    float vvR = __shfl_down(vva, 1, 32);              // vv[w0+2] (lane31 gives 0)
    if (l == 0) vvL = 0.f;                            // col -1 pad
    int h = r - 1;
    if (h >= h0s && h <= hend && l < 31) {
      f32x2 o;
      o[0] = cst + q0 * vvL + q1 * vva + q2 * vvb;
      o[1] = cst + q0 * vva + q1 * vvb + q2 * vvR;
      *(f32x2*)(dst + h * OW + w0) = o;
    }
  }
}

extern "C" void kernel_launch(void* const* d_in, const int* in_sizes, int n_in,
                              void* d_out, int out_size, void* d_ws, size_t ws_size,
                              hipStream_t stream) {
  const float* x   = (const float*)d_in[0];
  const float* L1w = (const float*)d_in[1];
  const float* L1b = (const float*)d_in[2];
  const float* V1w = (const float*)d_in[3];
  const float* V1b = (const float*)d_in[4];
  const float* H1w = (const float*)d_in[5];
  const float* H1b = (const float*)d_in[6];
  const float* L2w = (const float*)d_in[7];
  const float* L2b = (const float*)d_in[8];
  const float* V2w = (const float*)d_in[9];
  const float* V2b = (const float*)d_in[10];
  const float* H2w = (const float*)d_in[11];
  const float* H2b = (const float*)d_in[12];

  char* ws = (char*)d_ws;
  ushort* y1n = (ushort*)ws;                                 // 67,108,864 B
  ushort* w1t = (ushort*)(ws + (size_t)67108864);            //     65,536 B
  ushort* w2t = (ushort*)(ws + (size_t)67108864 + 65536);    //    131,072 B
  ushort* t2n = (ushort*)ws;                                 // reuse y1n (dead), stride OPST
  ushort* t1n = (ushort*)d_out;                              // d_out scratch, stride OPST

  k_wt<<<dim3((CIN * CO + 255) / 256), dim3(256), 0, stream>>>(L1w, w1t, CIN, CO);
  k_wt<<<dim3((CO * CO + 255) / 256), dim3(256), 0, stream>>>(L2w, w2t, CO, CO);

  // L1: x (fp32 NCHW) -> y1n bf16 NCHW [b][256][4096]
  k_gemm<true><<<dim3(HW / 128, BB), dim3(512), 0, stream>>>(
      (const void*)x, w1t, L1b, y1n, HW, HW, CIN);

  // V1+H1 -> t1n bf16 [b][256][OPST] (in d_out)
  k_dw1<<<dim3(CO, BB), dim3(256), 0, stream>>>(y1n, V1w, V1b, H1w, H1b, t1n);

  // L2: t1n -> t2n bf16 [b][256][OPST]
  k_gemm<false><<<dim3(OPST / 128, BB), dim3(512), 0, stream>>>(
      (const void*)t1n, w2t, L2b, t2n, OPST, OPST, CO);

  // pad + V2 + H2 -> d_out fp32 NCHW
  k_dw2<<<dim3(CO, BB), dim3(256), 0, stream>>>(t2n, V2w, V2b, H2w, H2b, (float*)d_out);
}